// Round 2
// baseline (111.657 us; speedup 1.0000x reference)
//
#include <hip/hip_runtime.h>

// FsCoding10 fast-forward: per element,
//   v = |x|; z = 0; out = 0
//   for t in 0..15: v -= z*h[t]; z = ((v - T[t])/(|v|+1) > 0); out += z*d[t]
//   return out * sign(x)
// |v|+1 > 0 always and fp32 subtraction of distinct values never rounds to 0,
// so z == (v > T[t]) exactly -> no division needed.
// z*h and z*d are exact (z in {0,1}); fmaf rounds once like numpy's mul+add.
//
// Round 2: pairwise f32x2 processing (targets v_pk_fma_f32, cuts per-step
// VALU from 8 to 6 per 2 elements) + 2 coalesced float4 streams per thread
// per iteration (2 outstanding loads, fewer vmcnt serialization points).

#define NTHREADS 256
#define NBLOCKS  8192

typedef float f32x2 __attribute__((ext_vector_type(2)));

__device__ __forceinline__ f32x2 fs10_pair(f32x2 xi) {
    constexpr float H[16] = {
        -0.11408895f, 1.1758447f, 1.0135335f, 1.2213913f,
         1.3241712f,  0.8555309f, 1.4268297f, 1.1778928f,
         0.80728793f, 0.43790972f, 0.2571573f, 0.13942857f,
        -0.3750314f,  0.08095932f, 1.354895f,  5.0583024f};
    constexpr float D[16] = {
         1.1759424f,  1.0134453f, 1.221452f,  1.3243698f,
         0.85503244f, 1.4270093f, 1.1782365f, 0.8076809f,
         0.43830687f, 0.2571347f, 0.13936771f, -0.04276754f,
         0.07785574f, 0.05046117f, 0.10240205f, 0.02330057f};
    constexpr float T[16] = {
         1.3393638f,  1.3052133f, 1.3697962f, 1.3982388f,
         1.264561f,   1.3956275f, 1.1693456f, 0.79711413f,
         0.42847168f, 0.24717589f, 0.13019533f, 0.52669114f,
         0.06617433f, 0.0366448f, 1.0000271f, 0.01022558f};

    f32x2 v, z, a;
    v.x = fabsf(xi.x);
    v.y = fabsf(xi.y);
    // Step 0: z==0 entering, so v is unchanged; just compare and init acc.
    z.x = (v.x > T[0]) ? 1.0f : 0.0f;
    z.y = (v.y > T[0]) ? 1.0f : 0.0f;
    a.x = z.x * D[0];   // exact: z in {0,1}
    a.y = z.y * D[0];
#pragma unroll
    for (int t = 1; t < 16; ++t) {
        const f32x2 nh = {-H[t], -H[t]};
        const f32x2 dd = { D[t],  D[t]};
        v = __builtin_elementwise_fma(z, nh, v);  // v -= z*h[t]   (pk_fma)
        z.x = (v.x > T[t]) ? 1.0f : 0.0f;         // spike == (v > T)
        z.y = (v.y > T[t]) ? 1.0f : 0.0f;
        a = __builtin_elementwise_fma(z, dd, a);  // acc += z*d[t] (pk_fma)
    }
    f32x2 r;
    r.x = copysignf(a.x, xi.x);  // out * sign(x); a==0 when x==0
    r.y = copysignf(a.y, xi.y);
    return r;
}

__device__ __forceinline__ float4 fs10_quad(float4 xv) {
    f32x2 lo = {xv.x, xv.y}, hi = {xv.z, xv.w};
    f32x2 rlo = fs10_pair(lo), rhi = fs10_pair(hi);
    float4 r;
    r.x = rlo.x; r.y = rlo.y; r.z = rhi.x; r.w = rhi.y;
    return r;
}

__global__ __launch_bounds__(NTHREADS)
void fs10_kernel(const float4* __restrict__ x, float4* __restrict__ out,
                 int n4, const float* __restrict__ xs, float* __restrict__ outs,
                 int n) {
    const int stride = gridDim.x * blockDim.x;
    int i = blockIdx.x * blockDim.x + threadIdx.x;

    // Main loop: 2 coalesced float4 streams per iteration; both loads issued
    // before compute, both stores after (2 outstanding VMEM ops per wave).
    for (; i + stride < n4; i += 2 * stride) {
        float4 xa = x[i];
        float4 xb = x[i + stride];
        float4 ra = fs10_quad(xa);
        float4 rb = fs10_quad(xb);
        out[i]          = ra;
        out[i + stride] = rb;
    }
    // Remainder float4s (n4 not a multiple of 2*stride).
    for (; i < n4; i += stride) {
        out[i] = fs10_quad(x[i]);
    }
    // Scalar tail (n % 4 != 0) — not hit for this problem size.
    const int tail_base = n4 << 2;
    for (int j = tail_base + blockIdx.x * blockDim.x + threadIdx.x; j < n;
         j += stride) {
        f32x2 p = {xs[j], 0.0f};
        outs[j] = fs10_pair(p).x;
    }
}

extern "C" void kernel_launch(void* const* d_in, const int* in_sizes, int n_in,
                              void* d_out, int out_size, void* d_ws, size_t ws_size,
                              hipStream_t stream) {
    const float* x = (const float*)d_in[0];
    float* out     = (float*)d_out;
    const int n    = in_sizes[0];
    const int n4   = n >> 2;

    int blocks = (n4 + NTHREADS - 1) / NTHREADS;
    if (blocks > NBLOCKS) blocks = NBLOCKS;
    if (blocks < 1) blocks = 1;

    fs10_kernel<<<blocks, NTHREADS, 0, stream>>>(
        (const float4*)x, (float4*)out, n4, x, out, n);
}

// Round 4
// 107.138 us; speedup vs baseline: 1.0422x; 1.0422x over previous
//
#include <hip/hip_runtime.h>

// FsCoding10 fast-forward: per element,
//   v = |x|; z = 0; out = 0
//   for t in 0..15: v -= z*h[t]; z = ((v - T[t])/(|v|+1) > 0); out += z*d[t]
//   return out * sign(x)
// |v|+1 > 0 always and fp32 subtraction of distinct values never rounds to 0,
// so z == (v > T[t]) exactly -> no division needed.
// z*h and z*d are exact (z in {0,1}); fmaf rounds once like numpy's mul+add.
//
// Round 4: same as R3 (nontemporal streaming) but with clang ext-vector
// float4 (HIP_vector_type struct is rejected by the nontemporal builtins).

#define NTHREADS 256
#define NBLOCKS  8192

typedef float f32x2 __attribute__((ext_vector_type(2)));
typedef float f32x4 __attribute__((ext_vector_type(4)));

__device__ __forceinline__ f32x2 fs10_pair(f32x2 xi) {
    constexpr float H[16] = {
        -0.11408895f, 1.1758447f, 1.0135335f, 1.2213913f,
         1.3241712f,  0.8555309f, 1.4268297f, 1.1778928f,
         0.80728793f, 0.43790972f, 0.2571573f, 0.13942857f,
        -0.3750314f,  0.08095932f, 1.354895f,  5.0583024f};
    constexpr float D[16] = {
         1.1759424f,  1.0134453f, 1.221452f,  1.3243698f,
         0.85503244f, 1.4270093f, 1.1782365f, 0.8076809f,
         0.43830687f, 0.2571347f, 0.13936771f, -0.04276754f,
         0.07785574f, 0.05046117f, 0.10240205f, 0.02330057f};
    constexpr float T[16] = {
         1.3393638f,  1.3052133f, 1.3697962f, 1.3982388f,
         1.264561f,   1.3956275f, 1.1693456f, 0.79711413f,
         0.42847168f, 0.24717589f, 0.13019533f, 0.52669114f,
         0.06617433f, 0.0366448f, 1.0000271f, 0.01022558f};

    f32x2 v, z, a;
    v.x = fabsf(xi.x);
    v.y = fabsf(xi.y);
    // Step 0: z==0 entering, so v is unchanged; just compare and init acc.
    z.x = (v.x > T[0]) ? 1.0f : 0.0f;
    z.y = (v.y > T[0]) ? 1.0f : 0.0f;
    a.x = z.x * D[0];   // exact: z in {0,1}
    a.y = z.y * D[0];
#pragma unroll
    for (int t = 1; t < 16; ++t) {
        const f32x2 nh = {-H[t], -H[t]};
        const f32x2 dd = { D[t],  D[t]};
        v = __builtin_elementwise_fma(z, nh, v);  // v -= z*h[t]   (pk_fma)
        z.x = (v.x > T[t]) ? 1.0f : 0.0f;         // spike == (v > T)
        z.y = (v.y > T[t]) ? 1.0f : 0.0f;
        a = __builtin_elementwise_fma(z, dd, a);  // acc += z*d[t] (pk_fma)
    }
    f32x2 r;
    r.x = copysignf(a.x, xi.x);  // out * sign(x); a==0 when x==0
    r.y = copysignf(a.y, xi.y);
    return r;
}

__device__ __forceinline__ f32x4 fs10_quad(f32x4 xv) {
    f32x2 lo = {xv.x, xv.y}, hi = {xv.z, xv.w};
    f32x2 rlo = fs10_pair(lo), rhi = fs10_pair(hi);
    f32x4 r;
    r.x = rlo.x; r.y = rlo.y; r.z = rhi.x; r.w = rhi.y;
    return r;
}

__global__ __launch_bounds__(NTHREADS)
void fs10_kernel(const f32x4* __restrict__ x, f32x4* __restrict__ out,
                 int n4, const float* __restrict__ xs, float* __restrict__ outs,
                 int n) {
    const int stride = gridDim.x * blockDim.x;
    int i = blockIdx.x * blockDim.x + threadIdx.x;

    // Main loop: 2 coalesced float4 streams per iteration, nontemporal.
    for (; i + stride < n4; i += 2 * stride) {
        f32x4 xa = __builtin_nontemporal_load(&x[i]);
        f32x4 xb = __builtin_nontemporal_load(&x[i + stride]);
        f32x4 ra = fs10_quad(xa);
        f32x4 rb = fs10_quad(xb);
        __builtin_nontemporal_store(ra, &out[i]);
        __builtin_nontemporal_store(rb, &out[i + stride]);
    }
    // Remainder float4s (n4 not a multiple of 2*stride).
    for (; i < n4; i += stride) {
        f32x4 xv = __builtin_nontemporal_load(&x[i]);
        __builtin_nontemporal_store(fs10_quad(xv), &out[i]);
    }
    // Scalar tail (n % 4 != 0) — not hit for this problem size.
    const int tail_base = n4 << 2;
    for (int j = tail_base + blockIdx.x * blockDim.x + threadIdx.x; j < n;
         j += stride) {
        f32x2 p = {xs[j], 0.0f};
        outs[j] = fs10_pair(p).x;
    }
}

extern "C" void kernel_launch(void* const* d_in, const int* in_sizes, int n_in,
                              void* d_out, int out_size, void* d_ws, size_t ws_size,
                              hipStream_t stream) {
    const float* x = (const float*)d_in[0];
    float* out     = (float*)d_out;
    const int n    = in_sizes[0];
    const int n4   = n >> 2;

    int blocks = (n4 + NTHREADS - 1) / NTHREADS;
    if (blocks > NBLOCKS) blocks = NBLOCKS;
    if (blocks < 1) blocks = 1;

    fs10_kernel<<<blocks, NTHREADS, 0, stream>>>(
        (const f32x4*)x, (f32x4*)out, n4, x, out, n);
}